// Round 1
// 218.482 us; speedup vs baseline: 1.0087x; 1.0087x over previous
//
#include <hip/hip_runtime.h>

// ---------------------------------------------------------------------------
// RelGraphConv x3 + action mask, MI355X (gfx950) — round 9
// R8 analysis: every kernel < 43 µs (all top-5 rocprof dispatches are the
// harness's 256 MB poison fills); sum of roofline work ~60-80 µs vs 220 µs
// measured -> serial dispatch-boundary overhead dominates. This round:
// 8 -> 5 dispatches.
//   * AG2 fuses phaseB + agg1 + gemm2: block = 64 nodes (half a bin),
//     eidx built in LDS (mirrored to global for later layers), post-relu H1
//     lives only in LDS (kills 12.8 MB round-trip), layer-2 MFMA from LDS.
//   * a3m_mask fuses agg3min + mask with a co-resident spin barrier
//     (196 blocks << capacity; device-scope atomics at coherent point, safe
//     under XCD L2 non-coherence). H3 final write deleted (stays in regs).
// K0 (pack+init) and K1 (phaseA || gemm1) and k3 unchanged.
// ---------------------------------------------------------------------------

#define STRIDE 64    // bucket capacity; P(deg>=64) astronomically small
#define BINCAP 2560  // records per bin; mean 2048, sigma~45 -> 11 sigma margin

typedef unsigned short ushortT;
typedef __attribute__((ext_vector_type(8))) short short8;   // 8 bf16 (4 VGPRs)
typedef __attribute__((ext_vector_type(4))) float f32x4;    // MFMA C/D

__device__ inline ushortT f2bf(float f) {
    union { float f; unsigned u; } v; v.f = f;
    unsigned r = v.u + 0x7FFFu + ((v.u >> 16) & 1u);   // RNE
    return (ushortT)(r >> 16);
}
__device__ inline float bf2f(ushortT h) {
    union { unsigned u; float f; } v; v.u = ((unsigned)h) << 16;
    return v.f;
}

__device__ inline void atomicMinF(float* addr, float v) {
    if (v >= 0.f) atomicMin((int*)addr, __float_as_int(v));
    else          atomicMax((unsigned int*)addr, __float_as_uint(v));
}

// ---- K0: weight pack + bincnt/minval/done init -----------------------------
__global__ __launch_bounds__(256) void pack_init_kernel(
    const float* __restrict__ W1, const float* __restrict__ loop1,
    const float* __restrict__ W2, const float* __restrict__ loop2,
    ushortT* __restrict__ BP1, ushortT* __restrict__ BP2,
    int* __restrict__ bincnt, float* __restrict__ minval,
    int* __restrict__ done, int NBINS) {
    int g = (int)blockIdx.x * 256 + (int)threadIdx.x;  // 0..4607
    if (g < NBINS) bincnt[g] = 0;
    if (g == 0) { *(int*)minval = 0x7f7f7f7f; *done = 0; }
    if (g < 3072) {
        // layer 1: 12 ct x 4 ks x 64 lanes
        int l = g & 63, ks = (g >> 6) & 3, ct = g >> 8;
        int c = ct * 16 + (l & 15);
        int mat = c >> 6, cc = c & 63;
        int kbase = ks * 32 + (l >> 4) * 8;
        ushortT* dstp = BP1 + (size_t)g * 8;
#pragma unroll
        for (int j = 0; j < 8; ++j) {
            int k = kbase + j;
            float v = (mat < 2) ? W1[((size_t)mat * 128 + k) * 64 + cc]
                                : loop1[(size_t)k * 64 + cc];
            dstp[j] = f2bf(v);
        }
    } else {
        // layer 2: 12 ct x 2 ks x 64 lanes
        int s = g - 3072;
        int l = s & 63, ks = (s >> 6) & 1, ct = s >> 7;
        int c = ct * 16 + (l & 15);
        int mat = c >> 6, cc = c & 63;
        int kbase = ks * 32 + (l >> 4) * 8;
        ushortT* dstp = BP2 + (size_t)s * 8;
#pragma unroll
        for (int j = 0; j < 8; ++j) {
            int k = kbase + j;
            float v = (mat < 2) ? W2[((size_t)mat * 64 + k) * 64 + cc]
                                : loop2[(size_t)k * 64 + cc];
            dstp[j] = f2bf(v);
        }
    }
}

// ---- K1: phaseA-binning [0,NBA) | gemm1 [NBA, NBA+NTILES) ------------------
__global__ __launch_bounds__(256) void k1_kernel(
    const float* __restrict__ x, const ushortT* __restrict__ BP1,
    const float* __restrict__ b1,
    ushortT* __restrict__ hrelb, ushortT* __restrict__ H1b,
    const int* __restrict__ src, const int* __restrict__ dst,
    const int* __restrict__ et, int* __restrict__ bincnt, int2* __restrict__ binbuf,
    int N, int E, int NBINS, int NBA) {
    __shared__ int hist[512];
    __shared__ int gbase[512];
    __shared__ ushortT rnk[4096];

    const int t = (int)threadIdx.x;

    if ((int)blockIdx.x < NBA) {
        // ---- phase A: bin 4096 edges ---------------------------------------
        for (int i = t; i < NBINS; i += 256) hist[i] = 0;
        __syncthreads();
        const int base = (int)blockIdx.x * 4096;
#pragma unroll
        for (int i = 0; i < 16; ++i) {
            int e = base + t + i * 256;
            if (e < E) {
                int bb = dst[e] >> 7;
                rnk[t + i * 256] = (ushortT)atomicAdd(&hist[bb], 1);
            }
        }
        __syncthreads();
        for (int i = t; i < NBINS; i += 256) {
            int h = hist[i];
            gbase[i] = h ? atomicAdd(&bincnt[i], h) : 0;
        }
        __syncthreads();
#pragma unroll
        for (int i = 0; i < 16; ++i) {
            int e = base + t + i * 256;
            if (e < E) {
                int dd = dst[e];
                int bb = dd >> 7;
                int v = et[e] * N + src[e];
                int pos = gbase[bb] + (int)rnk[t + i * 256];
                if (pos < BINCAP)
                    binbuf[(size_t)bb * BINCAP + pos] = make_int2(dd, v);
            }
        }
        return;
    }
    // ---- gemm1 (MFMA): wave = 16 nodes x 192 cols, K=128, no LDS use -------
    const int w = t >> 6, lane = t & 63;
    const int rowbase = (((int)blockIdx.x - NBA) * 4 + w) * 16;
    const int m = lane & 15, quad = lane >> 4;
    const int nclamp = min(rowbase + m, N - 1);

    short8 a[4];
    const float* xp = x + (size_t)nclamp * 128 + quad * 8;
#pragma unroll
    for (int ks = 0; ks < 4; ++ks) {
        float4 g0 = *(const float4*)(xp + ks * 32);
        float4 g1 = *(const float4*)(xp + ks * 32 + 4);
        a[ks][0] = (short)f2bf(g0.x); a[ks][1] = (short)f2bf(g0.y);
        a[ks][2] = (short)f2bf(g0.z); a[ks][3] = (short)f2bf(g0.w);
        a[ks][4] = (short)f2bf(g1.x); a[ks][5] = (short)f2bf(g1.y);
        a[ks][6] = (short)f2bf(g1.z); a[ks][7] = (short)f2bf(g1.w);
    }

    f32x4 acc[12];
#pragma unroll
    for (int ct = 0; ct < 12; ++ct) acc[ct] = (f32x4){0.f, 0.f, 0.f, 0.f};

#pragma unroll
    for (int ks = 0; ks < 4; ++ks) {
#pragma unroll
        for (int ct = 0; ct < 12; ++ct) {
            short8 b = *(const short8*)&BP1[((size_t)(ct * 4 + ks) * 64 + lane) * 8];
            acc[ct] = __builtin_amdgcn_mfma_f32_16x16x32_bf16(a[ks], b, acc[ct], 0, 0, 0);
        }
    }

    const int node0 = rowbase + quad * 4;
#pragma unroll
    for (int ct = 0; ct < 12; ++ct) {
        int c = ct * 16 + m;
        int mat = c >> 6, cc = c & 63;
        float bias = (mat == 2) ? b1[cc] : 0.f;
#pragma unroll
        for (int j = 0; j < 4; ++j) {
            int n = node0 + j;
            if (n < N) {
                float v = acc[ct][j] + bias;
                if (mat < 2) hrelb[((size_t)mat * N + n) * 64 + cc] = f2bf(v);
                else         H1b[(size_t)n * 64 + cc] = f2bf(v);
            }
        }
    }
}

// ---- AG2: fused phaseB (half-bin) + agg(layer1) + gemm2 (MFMA) -------------
// block = 512 threads = 8 waves, owns 64 nodes (= half of bin blockIdx>>1).
// phase0: scan bin records -> eidx rows in LDS (+ mirror to global).
// phase1: wave aggregates 8 nodes (lane = channel), relu -> LDS bf16 tile.
// phase2: layer-2 MFMA straight from LDS (4 row-tiles x 2 col-halves).
__global__ __launch_bounds__(512, 4) void ag2_kernel(
    const ushortT* __restrict__ hrelb, const ushortT* __restrict__ H1b,
    const ushortT* __restrict__ BP2, const float* __restrict__ b2,
    const int* __restrict__ bincnt, const int2* __restrict__ binbuf,
    int* __restrict__ eidx, int* __restrict__ cnt,
    ushortT* __restrict__ hrel2b, ushortT* __restrict__ H2b, int N) {
    __shared__ int lcnt[64];
    __shared__ int lidx[64][STRIDE];                       // 16 KB
    __shared__ __align__(16) ushortT Hs[64][72];           // 9.2 KB, +8 pad: 2-way banks

    const int t = (int)threadIdx.x;
    const int B = (int)blockIdx.x;
    const int nodeBase = B * 64;
    const int bin = B >> 1;

    if (t < 64) lcnt[t] = 0;
    __syncthreads();

    // ---- phase 0: filter bin records for our 64 nodes ----------------------
    const int cb = min(bincnt[bin], BINCAP);
    const int2* buf = binbuf + (size_t)bin * BINCAP;
    for (int i = t; i < cb; i += 512) {
        int2 rec = buf[i];
        int local = rec.x - nodeBase;
        if ((unsigned)local < 64u) {
            int r = atomicAdd(&lcnt[local], 1);
            if (r < STRIDE) {
                lidx[local][r] = rec.y;
                eidx[(size_t)rec.x * STRIDE + r] = rec.y;   // for k3 / a3m
            }
        }
    }
    __syncthreads();
    if (t < 64) {
        int c = min(lcnt[t], STRIDE);
        lcnt[t] = c;
        int node = nodeBase + t;
        if (node < N) cnt[node] = c;
    }
    __syncthreads();

    const int w = t >> 6, lane = t & 63;

    // ---- phase 1: aggregate 8 nodes per wave, lane = channel ---------------
    for (int i = 0; i < 8; ++i) {
        int local = w * 8 + i;
        int node = nodeBase + local;
        if (node >= N) { Hs[local][lane] = 0; continue; }
        int deg = lcnt[local];
        float acc = bf2f(H1b[(size_t)node * 64 + lane]);   // self-loop + bias
        int j = 0;
        for (; j + 7 < deg; j += 8) {
            float v[8];
#pragma unroll
            for (int q = 0; q < 8; ++q) {
                int id = lidx[local][j + q];               // LDS broadcast, free
                v[q] = bf2f(hrelb[(size_t)id * 64 + lane]);
            }
            acc += ((v[0] + v[1]) + (v[2] + v[3])) + ((v[4] + v[5]) + (v[6] + v[7]));
        }
        for (; j < deg; ++j)
            acc += bf2f(hrelb[(size_t)lidx[local][j] * 64 + lane]);
        Hs[local][lane] = f2bf(fmaxf(acc, 0.f));           // relu, LDS only
    }
    __syncthreads();

    // ---- phase 2: gemm2, wave = 16 rows x 96 cols, K=64 --------------------
    const int rt = w & 3, h = w >> 2;
    const int m = lane & 15, quad = lane >> 4;
    short8 a[2];
#pragma unroll
    for (int ks = 0; ks < 2; ++ks)
        a[ks] = *(const short8*)&Hs[rt * 16 + m][quad * 8 + ks * 32];

    f32x4 acc[6];
#pragma unroll
    for (int c6 = 0; c6 < 6; ++c6) acc[c6] = (f32x4){0.f, 0.f, 0.f, 0.f};

#pragma unroll
    for (int ks = 0; ks < 2; ++ks) {
#pragma unroll
        for (int c6 = 0; c6 < 6; ++c6) {
            int ct = h * 6 + c6;
            short8 b = *(const short8*)&BP2[((size_t)(ct * 2 + ks) * 64 + lane) * 8];
            acc[c6] = __builtin_amdgcn_mfma_f32_16x16x32_bf16(a[ks], b, acc[c6], 0, 0, 0);
        }
    }

    const int node0 = nodeBase + rt * 16 + quad * 4;
#pragma unroll
    for (int c6 = 0; c6 < 6; ++c6) {
        int ct = h * 6 + c6;
        int c = ct * 16 + m;
        int mat = c >> 6, cc = c & 63;
        float bias = (mat == 2) ? b2[cc] : 0.f;
#pragma unroll
        for (int j = 0; j < 4; ++j) {
            int n = node0 + j;
            if (n < N) {
                float v = acc[c6][j] + bias;
                if (mat < 2) hrel2b[((size_t)mat * N + n) * 64 + cc] = f2bf(v);
                else         H2b[(size_t)n * 64 + cc] = f2bf(v);
            }
        }
    }
}

// ---- K3: fused agg(layer2) + gemm(layer3, out=2), wave per node ------------
__global__ void k3_kernel(const ushortT* __restrict__ hrel2b, const ushortT* __restrict__ H2b,
                          const int* __restrict__ eidx, const int* __restrict__ cnt,
                          const float* __restrict__ W3, const float* __restrict__ loop3,
                          const float* __restrict__ b3,
                          float* __restrict__ hrel3, float* __restrict__ H3, int N) {
    int node = (int)blockIdx.x * 4 + ((int)threadIdx.x >> 6);
    if (node >= N) return;
    int lane = (int)threadIdx.x & 63;
    int deg = cnt[node];
    int my = (lane < deg) ? eidx[(size_t)node * STRIDE + lane] : 0;
    float acc = bf2f(H2b[(size_t)node * 64 + lane]);
    int j = 0;
    for (; j + 7 < deg; j += 8) {
        int id[8];
        float v[8];
#pragma unroll
        for (int q = 0; q < 8; ++q) id[q] = __shfl(my, j + q, 64);
#pragma unroll
        for (int q = 0; q < 8; ++q) v[q] = bf2f(hrel2b[(size_t)id[q] * 64 + lane]);
        acc += ((v[0] + v[1]) + (v[2] + v[3])) + ((v[4] + v[5]) + (v[6] + v[7]));
    }
    for (; j < deg; ++j)
        acc += bf2f(hrel2b[(size_t)__shfl(my, j, 64) * 64 + lane]);
    float xk = fmaxf(acc, 0.f);  // relu(layer-2 out), lane = k
    float p[6];
    p[0] = xk * W3[lane * 2 + 0];
    p[1] = xk * W3[lane * 2 + 1];
    p[2] = xk * W3[(64 + lane) * 2 + 0];
    p[3] = xk * W3[(64 + lane) * 2 + 1];
    p[4] = xk * loop3[lane * 2 + 0];
    p[5] = xk * loop3[lane * 2 + 1];
#pragma unroll
    for (int mm = 32; mm >= 1; mm >>= 1) {
#pragma unroll
        for (int q = 0; q < 6; ++q) p[q] += __shfl_xor(p[q], mm, 64);
    }
    if (lane == 0) {
        hrel3[(size_t)node * 2 + 0] = p[0];
        hrel3[(size_t)node * 2 + 1] = p[1];
        hrel3[((size_t)N + node) * 2 + 0] = p[2];
        hrel3[((size_t)N + node) * 2 + 1] = p[3];
        H3[(size_t)node * 2 + 0] = p[4] + b3[0];
        H3[(size_t)node * 2 + 1] = p[5] + b3[1];
    }
}

// ---- A3M+MASK: layer-3 agg + global min (co-resident spin barrier) + mask --
// grid = 196 blocks x 256 thr, far below co-residency capacity -> safe spin.
// All cross-block communication via device-scope atomics at the coherent
// point (XCD L2s are not coherent; plain loads would be unsafe).
__global__ __launch_bounds__(256) void a3m_mask_kernel(
    const float* __restrict__ hrel3, const int* __restrict__ eidx,
    const int* __restrict__ cnt, const float* __restrict__ H3,
    const int* __restrict__ cs, const int* __restrict__ ms,
    float* __restrict__ minval, int* __restrict__ done,
    float* __restrict__ out, int N) {
    const int t = (int)threadIdx.x;
    const int n = (int)blockIdx.x * 256 + t;
    float a0 = 0.f, a1 = 0.f;
    float v = 3.4e38f;
    if (n < N) {
        a0 = H3[n * 2 + 0]; a1 = H3[n * 2 + 1];
        int deg = cnt[n];
        const int* row = &eidx[(size_t)n * STRIDE];
        int j = 0;
        for (; j + 3 < deg; j += 4) {
            int i0 = row[j], i1 = row[j + 1], i2 = row[j + 2], i3 = row[j + 3];
            float2 q0 = *(const float2*)&hrel3[(size_t)i0 * 2];
            float2 q1 = *(const float2*)&hrel3[(size_t)i1 * 2];
            float2 q2 = *(const float2*)&hrel3[(size_t)i2 * 2];
            float2 q3 = *(const float2*)&hrel3[(size_t)i3 * 2];
            a0 += (q0.x + q1.x) + (q2.x + q3.x);
            a1 += (q0.y + q1.y) + (q2.y + q3.y);
        }
        for (; j < deg; ++j) {
            float2 q = *(const float2*)&hrel3[(size_t)row[j] * 2];
            a0 += q.x; a1 += q.y;
        }
        v = fminf(a0, a1);       // h.min() over FINAL h, before masking
    }
#pragma unroll
    for (int mm = 32; mm >= 1; mm >>= 1) v = fminf(v, __shfl_xor(v, mm, 64));
    __shared__ float s[4];
    __shared__ float gm;
    if ((t & 63) == 0) s[t >> 6] = v;
    __syncthreads();
    if (t == 0) {
        atomicMinF(minval, fminf(fminf(s[0], s[1]), fminf(s[2], s[3])));
        __threadfence();                        // order minval before done
        atomicAdd(done, 1);
        while (atomicAdd(done, 0) < (int)gridDim.x)  // device-scope atomic read
            __builtin_amdgcn_s_sleep(2);
        gm = atomicAdd(minval, 0.0f);           // atomic read of final min
    }
    __syncthreads();
    if (n < N) {
        float mn = gm - 1.0f;
        bool up = cs[n] >= ms[n] - 1;
        bool lo = cs[n] == 0;
        out[n * 2 + 0] = up ? mn : a0;
        out[n * 2 + 1] = lo ? mn : a1;
    }
}

// ---------------------------------------------------------------------------
extern "C" void kernel_launch(void* const* d_in, const int* in_sizes, int n_in,
                              void* d_out, int out_size, void* d_ws, size_t ws_size,
                              hipStream_t stream) {
    const float* x     = (const float*)d_in[0];
    const int* src     = (const int*)d_in[1];
    const int* dst     = (const int*)d_in[2];
    const int* etypes  = (const int*)d_in[3];
    const int* cellsz  = (const int*)d_in[4];
    const int* maxsz   = (const int*)d_in[5];
    const float* W1    = (const float*)d_in[6];
    const float* loop1 = (const float*)d_in[7];
    const float* b1    = (const float*)d_in[8];
    const float* W2    = (const float*)d_in[9];
    const float* loop2 = (const float*)d_in[10];
    const float* b2    = (const float*)d_in[11];
    const float* W3    = (const float*)d_in[12];
    const float* loop3 = (const float*)d_in[13];
    const float* b3    = (const float*)d_in[14];
    float* out = (float*)d_out;

    const int N = in_sizes[0] / 128;  // 50000
    const int E = in_sizes[1];        // 800000

    char* p = (char*)d_ws;
    auto alloc = [&](size_t bytes) -> void* {
        void* r = (void*)p;
        p += ((bytes + 255) / 256) * 256;
        return r;
    };
    ushortT* hrelb  = (ushortT*)alloc((size_t)2 * N * 64 * 2);  // 12.8 MB bf16
    ushortT* H1b    = (ushortT*)alloc((size_t)N * 64 * 2);      //  6.4 MB bf16 (pre-agg only)
    ushortT* hrel2b = (ushortT*)alloc((size_t)2 * N * 64 * 2);  // 12.8 MB bf16
    ushortT* H2b    = (ushortT*)alloc((size_t)N * 64 * 2);      //  6.4 MB bf16
    float* hrel3    = (float*)alloc((size_t)2 * N * 2 * 4);
    float* H3       = (float*)alloc((size_t)N * 2 * 4);
    int* cnt        = (int*)alloc((size_t)N * 4);
    int* eidx       = (int*)alloc((size_t)N * STRIDE * 4);      // 12.8 MB
    ushortT* BP1    = (ushortT*)alloc((size_t)3072 * 8 * 2);    // 48 KB frag-packed
    ushortT* BP2    = (ushortT*)alloc((size_t)1536 * 8 * 2);    // 24 KB
    float* minval   = (float*)alloc(4);
    int* done       = (int*)alloc(4);                           // own 256B chunk

    const int NBINS = (N + 127) >> 7;                           // 391
    int* bincnt     = (int*)alloc((size_t)NBINS * 4);
    int2* binbuf    = (int2*)alloc((size_t)NBINS * BINCAP * 8); // 8.0 MB
    (void)ws_size; (void)n_in; (void)out_size;

    const int NB_N   = (N + 255) / 256;      // 196
    const int NTILES = (N + 63) / 64;        // 782
    const int NB_W   = (N + 3) / 4;          // 12500
    const int NBA    = (E + 4095) / 4096;    // 196 phase-A blocks
    const int NB_AG  = (N + 63) / 64;        // 782 fused blocks (64 nodes each)

    // K0: weight pack + bincnt/minval/done init (producer ordering)
    pack_init_kernel<<<18, 256, 0, stream>>>(
        W1, loop1, W2, loop2, BP1, BP2, bincnt, minval, done, NBINS);

    // K1: phase-A binning || layer-1 MFMA GEMM (independent halves)
    k1_kernel<<<NBA + NTILES, 256, 0, stream>>>(
        x, BP1, b1, hrelb, H1b,
        src, dst, etypes, bincnt, binbuf, N, E, NBINS, NBA);

    // AG2: fused phaseB + agg(layer1) + gemm2
    ag2_kernel<<<NB_AG, 512, 0, stream>>>(
        hrelb, H1b, BP2, b2, bincnt, binbuf, eidx, cnt, hrel2b, H2b, N);

    // fused agg(layer2) + gemm(layer3)
    k3_kernel<<<NB_W, 256, 0, stream>>>(hrel2b, H2b, eidx, cnt, W3, loop3, b3,
                                        hrel3, H3, N);

    // fused layer-3 aggregation + global min (spin barrier) + mask
    a3m_mask_kernel<<<NB_N, 256, 0, stream>>>(hrel3, eidx, cnt, H3,
                                              cellsz, maxsz, minval, done, out, N);
}